// Round 19
// baseline (161.966 us; speedup 1.0000x reference)
//
#include <hip/hip_runtime.h>
#include <hip/hip_bf16.h>

// Sparse conv for MI355X (gfx950), fused output-stationary design
// (r18 frame; presum ELIMINATED -- slot-sum folded into MFMA K-dimension):
//   kA : rank-blocks (LDS nibble counters -> DIRECT-ROW slot table
//        [row][27][4] u32) + wt-blocks (kern -> bf16 W^T) + cast-blocks
//        (f32 -> bf16 fb, plus one zeroed row at index Nrows for empty slots).
//   kF : 256-thread blocks, wave owns 16 rows; acc D[64ch][16rows] in regs.
//        Per k: 8 unconditional gathers (empty slot -> zero row), then up to
//        4 slots x 8 MFMAs feeding raw fragments as B operands (A = W frags,
//        slot-independent; K-accumulation does the cell sum). Slots gated
//        wave-uniformly via __any. W double-buffered in LDS, 1 barrier/k.
//   k4 : overflow fixup (~500 pairs) recomputes feat.W, atomicAdd.
// Fallback to a pure-atomic kernel for exotic shapes / tiny ws.

typedef __bf16 bf16x8 __attribute__((ext_vector_type(8)));
typedef float f32x4 __attribute__((ext_vector_type(4)));

#define KOFF 27
#define SLOTK 4                 // slots per (row,k) cell
#define NSLOT (KOFF * SLOTK)    // 108 entries per row
#define OVFCAP 8192             // overflow list capacity (E[ovf] ~ 505)
#define WPAD 72                 // LDS pad for W tile
#define ROWCHUNK 8192           // rows per rank-block chunk
#define NIBW (ROWCHUNK / 8)     // 4 KB LDS nibble counters
#define ATHR 1024               // kA block size

// ---- kA: chunked rank-builder (direct-row slots) + W cast + feature cast ----
__global__ __launch_bounds__(ATHR) void kA_rank_cast(
    const float* __restrict__ feat, const float* __restrict__ kern,
    const int* __restrict__ nin, const int* __restrict__ nout,
    __bf16* __restrict__ fb, __bf16* __restrict__ wt,
    unsigned int* __restrict__ slots, int2* __restrict__ ovf,
    int* __restrict__ ovfcnt, int Lpairs, int nElems, int nchunk,
    int rankBlocks, int wtBlocks) {
  __shared__ unsigned int nib[NIBW];
  const int tid = threadIdx.x;
  if ((int)blockIdx.x < rankBlocks) {
    const int k = blockIdx.x / nchunk;
    const int chunk = blockIdx.x % nchunk;
    const int lo = chunk * ROWCHUNK;
    for (int i = tid; i < NIBW; i += ATHR) nib[i] = 0u;
    __syncthreads();
    const int* nkO = nout + k * Lpairs;
    const int* nkI = nin + k * Lpairs;
    const int STEP = ATHR * 8;  // 8192 pairs per iteration

    // depth-1 pipelined scan: load batch(base+STEP) while claiming batch(base)
    int l[8], row[8], rin[8], ln[8], rown[8], rinn[8];
#pragma unroll
    for (int j = 0; j < 8; ++j) {
      l[j] = j * ATHR + tid;
      row[j] = (l[j] < Lpairs) ? nkO[l[j]] : -1;
      rin[j] = (l[j] < Lpairs) ? nkI[l[j]] : 0;
    }
    for (int base = 0; base < Lpairs; base += STEP) {
      const int nbase = base + STEP;
      if (nbase < Lpairs) {
#pragma unroll
        for (int j = 0; j < 8; ++j) {
          ln[j] = nbase + j * ATHR + tid;
          rown[j] = (ln[j] < Lpairs) ? nkO[ln[j]] : -1;
          rinn[j] = (ln[j] < Lpairs) ? nkI[ln[j]] : 0;
        }
      }
#pragma unroll
      for (int j = 0; j < 8; ++j) {
        int rr = row[j] - lo;
        if (rr >= 0 && rr < ROWCHUNK) {
          unsigned int sh = ((unsigned)rr & 7u) * 4u;
          unsigned int old = atomicAdd(&nib[rr >> 3], 1u << sh);
          int rank = (old >> sh) & 15;
          if (rank < SLOTK) {
            slots[(size_t)row[j] * NSLOT + k * SLOTK + rank] =
                (unsigned int)rin[j];
          } else {
            int idx = atomicAdd(ovfcnt, 1);
            if (idx < OVFCAP) ovf[idx] = make_int2(row[j], k * Lpairs + l[j]);
          }
        }
      }
      if (nbase < Lpairs) {
#pragma unroll
        for (int j = 0; j < 8; ++j) {
          l[j] = ln[j];
          row[j] = rown[j];
          rin[j] = rinn[j];
        }
      }
    }
  } else if ((int)blockIdx.x < rankBlocks + wtBlocks) {
    // W transpose/cast: wt[k][c*64+i] = (bf16)kern[k*4096 + i*64 + c]
    int kc = (blockIdx.x - rankBlocks) * ATHR + tid;
    if (kc < KOFF * 64) {
      int k = kc >> 6, c = kc & 63;
      const float* src = kern + k * 4096 + c;
      __bf16* dst = wt + (size_t)kc * 64;
#pragma unroll
      for (int i0 = 0; i0 < 64; i0 += 8) {
        bf16x8 v;
#pragma unroll
        for (int q = 0; q < 8; ++q) v[q] = (__bf16)src[(i0 + q) * 64];
        *(bf16x8*)(dst + i0) = v;
      }
    }
  } else {
    int i = ((blockIdx.x - rankBlocks - wtBlocks) * ATHR + tid) * 8;
    if (i < nElems) {
      f32x4 a = *(const f32x4*)(feat + i);
      f32x4 b = *(const f32x4*)(feat + i + 4);
      bf16x8 v;
#pragma unroll
      for (int j = 0; j < 4; ++j) {
        v[j] = (__bf16)a[j];
        v[j + 4] = (__bf16)b[j];
      }
      *(bf16x8*)(fb + i) = v;
    } else if (i < nElems + 64) {
      // zero row at index Nrows: target of empty-slot gathers
      bf16x8 z = {};
      *(bf16x8*)(fb + i) = z;
    }
  }
}

// ---- kF: fused output-stationary GEMM (slot-sum in MFMA K-dim) ----
// Wave handles 16 rows. Lane (g=lane>>4, r=lane&15):
//   B operands per k: RAW gathered fragments of each slot's feature row
//   A operand: W[k]^T fragments from LDS (slot-independent)
//   D: col=r -> row, row=g*4+reg (+t*16) -> channel; persistent across k.
__global__ __launch_bounds__(256) void kF_fused(
    const __bf16* __restrict__ fb, const __bf16* __restrict__ wt,
    const unsigned int* __restrict__ slots, float* __restrict__ out,
    int Nrows) {
  __shared__ __bf16 ldsW[2][64 * WPAD];
  const int tid = threadIdx.x;
  const int wv = tid >> 6, lane = tid & 63;
  const int r = lane & 15, g = lane >> 4;
  int row = blockIdx.x * 64 + wv * 16 + r;
  if (row >= Nrows) row = Nrows - 1;  // duplicate rows write identical values
  const uint4* srow = (const uint4*)(slots + (size_t)row * NSLOT);

  // staging coords: thread copies W row c = tid>>2, elems [si, si+16)
  const int sc = tid >> 2;
  const int si = (tid & 3) * 16;

  // stage W[0]: pure vector copy (2 x 16B load, 2 x ds_write_b128)
  {
    const __bf16* wp = wt + sc * 64 + si;
    bf16x8 wa = *(const bf16x8*)(wp);
    bf16x8 wb = *(const bf16x8*)(wp + 8);
    *(bf16x8*)&ldsW[0][sc * WPAD + si] = wa;
    *(bf16x8*)&ldsW[0][sc * WPAD + si + 8] = wb;
  }

  // Cell pipeline: cur = k, nxt = k+1 (prefetched one body ahead).
  uint4 cellCur = srow[0];
  uint4 cellNxt = srow[1];

  f32x4 acc[4] = {f32x4{0.f, 0.f, 0.f, 0.f}, f32x4{0.f, 0.f, 0.f, 0.f},
                  f32x4{0.f, 0.f, 0.f, 0.f}, f32x4{0.f, 0.f, 0.f, 0.f}};
  __syncthreads();

  for (int k = 0; k < KOFF; ++k) {
    const int kb = k & 1;
    unsigned cc[4] = {cellCur.x, cellCur.y, cellCur.z, cellCur.w};
    // (1) 8 unconditional gathers (empty slot -> zero row at Nrows)
    bf16x8 fa[4], fc[4];
#pragma unroll
    for (int j = 0; j < 4; ++j) {
      unsigned rowj = cc[j] < (unsigned)Nrows ? cc[j] : (unsigned)Nrows;
      const __bf16* ap = fb + (size_t)rowj * 64 + g * 8;
      fa[j] = *(const bf16x8*)(ap);
      fc[j] = *(const bf16x8*)(ap + 32);
    }
    // (2) W-load(k+1) into regs
    bf16x8 wa, wb;
    if (k + 1 < KOFF) {
      const __bf16* wp = wt + (size_t)(k + 1) * 4096 + sc * 64 + si;
      wa = *(const bf16x8*)(wp);
      wb = *(const bf16x8*)(wp + 8);
    }
    // (3) cell(k+2)
    uint4 cv2 = make_uint4(~0u, ~0u, ~0u, ~0u);
    if (k + 2 < KOFF) cv2 = srow[k + 2];
    // (4) W fragments from LDS
    bf16x8 w0f[4], w1f[4];
#pragma unroll
    for (int t = 0; t < 4; ++t) {
      w0f[t] = *(const bf16x8*)&ldsW[kb][(t * 16 + r) * WPAD + g * 8];
      w1f[t] = *(const bf16x8*)&ldsW[kb][(t * 16 + r) * WPAD + g * 8 + 32];
    }
    // (5) slot-sum via MFMA K-accumulation; gate each slot wave-uniformly.
    //     acc[t] += W_half^T @ f_slot  (K=32 slices; zero rows are no-ops)
#pragma unroll
    for (int j = 0; j < 4; ++j) {
      if (__any((int)(cc[j] != 0xFFFFFFFFu))) {
#pragma unroll
        for (int t = 0; t < 4; ++t) {
          acc[t] = __builtin_amdgcn_mfma_f32_16x16x32_bf16(w0f[t], fa[j], acc[t], 0, 0, 0);
          acc[t] = __builtin_amdgcn_mfma_f32_16x16x32_bf16(w1f[t], fc[j], acc[t], 0, 0, 0);
        }
      }
    }
    // (6) ds_write W(k+1) into the other buffer + one barrier per k
    if (k + 1 < KOFF) {
      *(bf16x8*)&ldsW[kb ^ 1][sc * WPAD + si] = wa;
      *(bf16x8*)&ldsW[kb ^ 1][sc * WPAD + si + 8] = wb;
      __syncthreads();
    }
    // (7) rotate cell pipeline
    cellCur = cellNxt;
    cellNxt = cv2;
  }

  // Epilogue: lane (g,r) holds channels t*16+g*4+{0..3} of row.
  float* op = out + (size_t)row * 64;
#pragma unroll
  for (int t = 0; t < 4; ++t) *(f32x4*)(op + t * 16 + g * 4) = acc[t];
}

// ---- k4: overflow fixup (~500 pairs): recompute feat.W (bf16), atomicAdd ----
__global__ __launch_bounds__(256) void k4_fixup(
    const __bf16* __restrict__ fb, const __bf16* __restrict__ wt,
    const int* __restrict__ nin, const int2* __restrict__ ovf,
    const int* __restrict__ ovfcnt, float* __restrict__ out, int Lpairs) {
  int gid = blockIdx.x * 256 + threadIdx.x;
  int i = gid >> 6, c = gid & 63;
  int n = *ovfcnt;
  if (n > OVFCAP) n = OVFCAP;
  if (i >= n) return;
  int row = ovf[i].x, pid = ovf[i].y;
  int k = pid / Lpairs;
  int irow = nin[pid];
  const __bf16* wk = wt + ((size_t)k * 64 + c) * 64;  // wt[k][c][*]
  const __bf16* f = fb + (size_t)irow * 64;
  float s = 0.f;
#pragma unroll 8
  for (int q = 0; q < 64; ++q) s += (float)f[q] * (float)wk[q];
  atomicAdd(&out[(size_t)row * 64 + c], s);
}

// ---- Fallback: atomic kernel (exotic shapes / tiny ws) ----
__global__ __launch_bounds__(256) void spconv_atomic_kernel(
    const float* __restrict__ feat, const float* __restrict__ kern,
    const int* __restrict__ nin, const int* __restrict__ nout,
    float* __restrict__ out, int Lpairs, int blocksPerK) {
  __shared__ __bf16 ldsBT[64 * WPAD];
  const int bk = blockIdx.x / blocksPerK;
  const int chunk = blockIdx.x % blocksPerK;
  const float* kb = kern + bk * 4096;
  for (int idx = threadIdx.x; idx < 4096; idx += 256) {
    int i = idx >> 6, c = idx & 63;
    ldsBT[c * WPAD + i] = (__bf16)kb[idx];
  }
  __syncthreads();
  const int lane = threadIdx.x & 63;
  const int wave = threadIdx.x >> 6;
  const int r = lane & 15, g = lane >> 4;
  bf16x8 bfrag[2][4];
#pragma unroll
  for (int s = 0; s < 2; ++s)
#pragma unroll
    for (int t = 0; t < 4; ++t)
      bfrag[s][t] = *(const bf16x8*)&ldsBT[(t * 16 + r) * WPAD + g * 8 + s * 32];
  const int* ninK = nin + bk * Lpairs;
  const int* noutK = nout + bk * Lpairs;
  const int base0 = chunk * 512 + wave * 128;
  for (int it = 0; it < 8; ++it) {
    const int base = base0 + it * 16;
    if (base >= Lpairs) break;
    const int arow = ninK[base + r];
    const float* ap = feat + (size_t)arow * 64 + g * 8;
    f32x4 f0 = *(const f32x4*)(ap);
    f32x4 f1 = *(const f32x4*)(ap + 4);
    f32x4 f2 = *(const f32x4*)(ap + 32);
    f32x4 f3 = *(const f32x4*)(ap + 36);
    bf16x8 a0, a1;
#pragma unroll
    for (int j = 0; j < 4; ++j) {
      a0[j] = (__bf16)f0[j];
      a0[j + 4] = (__bf16)f1[j];
      a1[j] = (__bf16)f2[j];
      a1[j + 4] = (__bf16)f3[j];
    }
    f32x4 acc[4] = {f32x4{0.f, 0.f, 0.f, 0.f}, f32x4{0.f, 0.f, 0.f, 0.f},
                    f32x4{0.f, 0.f, 0.f, 0.f}, f32x4{0.f, 0.f, 0.f, 0.f}};
#pragma unroll
    for (int t = 0; t < 4; ++t) {
      acc[t] = __builtin_amdgcn_mfma_f32_16x16x32_bf16(a0, bfrag[0][t], acc[t], 0, 0, 0);
      acc[t] = __builtin_amdgcn_mfma_f32_16x16x32_bf16(a1, bfrag[1][t], acc[t], 0, 0, 0);
    }
    int orow[4];
#pragma unroll
    for (int reg = 0; reg < 4; ++reg) orow[reg] = noutK[base + g * 4 + reg];
#pragma unroll
    for (int t = 0; t < 4; ++t)
#pragma unroll
      for (int reg = 0; reg < 4; ++reg)
        atomicAdd(out + (size_t)orow[reg] * 64 + t * 16 + r, acc[t][reg]);
  }
}

extern "C" void kernel_launch(void* const* d_in, const int* in_sizes, int n_in,
                              void* d_out, int out_size, void* d_ws, size_t ws_size,
                              hipStream_t stream) {
  const float* feat = (const float*)d_in[0];
  const float* kern = (const float*)d_in[1];
  const int* nin = (const int*)d_in[2];
  const int* nout = (const int*)d_in[3];
  float* out = (float*)d_out;

  const int total = in_sizes[2];        // 27*L pairs
  const int Lpairs = total / KOFF;      // 50000
  const int Nrows = out_size / 64;      // 100000
  const int nElems = Nrows * 64;

  // ws layout: slots (u32 direct-row, 0xFF-init) | ovf | ovfcnt | wt | fb
  // fb has one extra zeroed row (index Nrows) as the empty-slot gather target.
  const size_t slotsBytes = (size_t)Nrows * NSLOT * 4;
  const size_t ovfOff = (slotsBytes + 255) & ~(size_t)255;
  const size_t cntOff = (ovfOff + (size_t)OVFCAP * 8 + 255) & ~(size_t)255;
  const size_t wtOff = (cntOff + 256 + 255) & ~(size_t)255;
  const size_t fbOff = (wtOff + (size_t)KOFF * 4096 * 2 + 255) & ~(size_t)255;
  const size_t needed = fbOff + (size_t)(nElems + 64) * 2;

  const bool shapeOK = (Lpairs % 16 == 0) && (total % KOFF == 0) &&
                       (out_size % 64 == 0);

  if (shapeOK && ws_size >= needed) {
    unsigned int* slots = (unsigned int*)d_ws;
    int2* ovf = (int2*)((char*)d_ws + ovfOff);
    int* ovfcnt = (int*)((char*)d_ws + cntOff);
    __bf16* wt = (__bf16*)((char*)d_ws + wtOff);
    __bf16* fb = (__bf16*)((char*)d_ws + fbOff);

    hipMemsetAsync(slots, 0xFF, slotsBytes, stream);
    hipMemsetAsync(ovfcnt, 0, 4, stream);

    const int nchunk = (Nrows + ROWCHUNK - 1) / ROWCHUNK;
    const int rankBlocks = KOFF * nchunk;
    const int wtBlocks = (KOFF * 64 + ATHR - 1) / ATHR;  // 2
    const int castBlocks = ((nElems + 64) / 8 + ATHR - 1) / ATHR;
    kA_rank_cast<<<rankBlocks + wtBlocks + castBlocks, ATHR, 0, stream>>>(
        feat, kern, nin, nout, fb, wt, slots, ovf, ovfcnt, Lpairs, nElems,
        nchunk, rankBlocks, wtBlocks);
    kF_fused<<<(Nrows + 63) / 64, 256, 0, stream>>>(fb, wt, slots, out, Nrows);
    k4_fixup<<<OVFCAP * 64 / 256, 256, 0, stream>>>(fb, wt, nin, ovf, ovfcnt,
                                                    out, Lpairs);
  } else {
    const int blocksPerK = (Lpairs + 511) / 512;
    hipMemsetAsync(d_out, 0, (size_t)out_size * sizeof(float), stream);
    spconv_atomic_kernel<<<KOFF * blocksPerK, 256, 0, stream>>>(
        feat, kern, nin, nout, out, Lpairs, blocksPerK);
  }
}

// Round 20
// 126.523 us; speedup vs baseline: 1.2801x; 1.2801x over previous
//
#include <hip/hip_runtime.h>
#include <hip/hip_bf16.h>

// Sparse conv for MI355X (gfx950), fused output-stationary design
// (r18 BEST-MEASURED config, resubmitted for consolidation):
//   kA : rank-blocks (LDS nibble counters -> DIRECT-ROW slot table
//        [row][27][4] u32) + wt-blocks (kern -> bf16 W^T) + cast-blocks
//        (f32 -> bf16 feature table fb). 1024 threads/block, depth-1 scan.
//   kF : 256-thread blocks, wave owns 16 rows; acc D[64ch][16rows] in regs
//        across all 27 k. Per k: 8 gathers from prefetched cell, presum
//        (linearity), 8 MFMAs vs W[k] from double-buffered LDS, 1 barrier/k.
//   k4 : overflow fixup (~500 pairs) recomputes feat.W, atomicAdd.
// Fallback to a pure-atomic kernel for exotic shapes / tiny ws.

typedef __bf16 bf16x8 __attribute__((ext_vector_type(8)));
typedef float f32x4 __attribute__((ext_vector_type(4)));

#define KOFF 27
#define SLOTK 4                 // slots per (row,k) cell
#define NSLOT (KOFF * SLOTK)    // 108 entries per row
#define OVFCAP 8192             // overflow list capacity (E[ovf] ~ 505)
#define WPAD 72                 // LDS pad for W tile
#define ROWCHUNK 8192           // rows per rank-block chunk
#define NIBW (ROWCHUNK / 8)     // 4 KB LDS nibble counters
#define ATHR 1024               // kA block size

// ---- kA: chunked rank-builder (direct-row slots) + W cast + feature cast ----
__global__ __launch_bounds__(ATHR) void kA_rank_cast(
    const float* __restrict__ feat, const float* __restrict__ kern,
    const int* __restrict__ nin, const int* __restrict__ nout,
    __bf16* __restrict__ fb, __bf16* __restrict__ wt,
    unsigned int* __restrict__ slots, int2* __restrict__ ovf,
    int* __restrict__ ovfcnt, int Lpairs, int nElems, int nchunk,
    int rankBlocks, int wtBlocks) {
  __shared__ unsigned int nib[NIBW];
  const int tid = threadIdx.x;
  if ((int)blockIdx.x < rankBlocks) {
    const int k = blockIdx.x / nchunk;
    const int chunk = blockIdx.x % nchunk;
    const int lo = chunk * ROWCHUNK;
    for (int i = tid; i < NIBW; i += ATHR) nib[i] = 0u;
    __syncthreads();
    const int* nkO = nout + k * Lpairs;
    const int* nkI = nin + k * Lpairs;
    const int STEP = ATHR * 8;  // 8192 pairs per iteration

    // depth-1 pipelined scan: load batch(base+STEP) while claiming batch(base)
    int l[8], row[8], rin[8], ln[8], rown[8], rinn[8];
#pragma unroll
    for (int j = 0; j < 8; ++j) {
      l[j] = j * ATHR + tid;
      row[j] = (l[j] < Lpairs) ? nkO[l[j]] : -1;
      rin[j] = (l[j] < Lpairs) ? nkI[l[j]] : 0;
    }
    for (int base = 0; base < Lpairs; base += STEP) {
      const int nbase = base + STEP;
      if (nbase < Lpairs) {
#pragma unroll
        for (int j = 0; j < 8; ++j) {
          ln[j] = nbase + j * ATHR + tid;
          rown[j] = (ln[j] < Lpairs) ? nkO[ln[j]] : -1;
          rinn[j] = (ln[j] < Lpairs) ? nkI[ln[j]] : 0;
        }
      }
#pragma unroll
      for (int j = 0; j < 8; ++j) {
        int rr = row[j] - lo;
        if (rr >= 0 && rr < ROWCHUNK) {
          unsigned int sh = ((unsigned)rr & 7u) * 4u;
          unsigned int old = atomicAdd(&nib[rr >> 3], 1u << sh);
          int rank = (old >> sh) & 15;
          if (rank < SLOTK) {
            slots[(size_t)row[j] * NSLOT + k * SLOTK + rank] =
                (unsigned int)rin[j];
          } else {
            int idx = atomicAdd(ovfcnt, 1);
            if (idx < OVFCAP) ovf[idx] = make_int2(row[j], k * Lpairs + l[j]);
          }
        }
      }
      if (nbase < Lpairs) {
#pragma unroll
        for (int j = 0; j < 8; ++j) {
          l[j] = ln[j];
          row[j] = rown[j];
          rin[j] = rinn[j];
        }
      }
    }
  } else if ((int)blockIdx.x < rankBlocks + wtBlocks) {
    // W transpose/cast: wt[k][c*64+i] = (bf16)kern[k*4096 + i*64 + c]
    int kc = (blockIdx.x - rankBlocks) * ATHR + tid;
    if (kc < KOFF * 64) {
      int k = kc >> 6, c = kc & 63;
      const float* src = kern + k * 4096 + c;
      __bf16* dst = wt + (size_t)kc * 64;
#pragma unroll
      for (int i0 = 0; i0 < 64; i0 += 8) {
        bf16x8 v;
#pragma unroll
        for (int q = 0; q < 8; ++q) v[q] = (__bf16)src[(i0 + q) * 64];
        *(bf16x8*)(dst + i0) = v;
      }
    }
  } else {
    int i = ((blockIdx.x - rankBlocks - wtBlocks) * ATHR + tid) * 8;
    if (i < nElems) {
      f32x4 a = *(const f32x4*)(feat + i);
      f32x4 b = *(const f32x4*)(feat + i + 4);
      bf16x8 v;
#pragma unroll
      for (int j = 0; j < 4; ++j) {
        v[j] = (__bf16)a[j];
        v[j + 4] = (__bf16)b[j];
      }
      *(bf16x8*)(fb + i) = v;
    }
  }
}

// ---- kF: fused output-stationary GEMM (r10 schedule, direct-row cells) ----
// Wave handles 16 rows. Lane (g=lane>>4, r=lane&15):
//   B operand per k: summed cell features of row (rowbase+r)
//   A operand: W[k]^T fragments from LDS (staged from wt via b128 copies)
//   D: col=r -> row, row=g*4+reg (+t*16) -> channel; persistent across k.
__global__ __launch_bounds__(256) void kF_fused(
    const __bf16* __restrict__ fb, const __bf16* __restrict__ wt,
    const unsigned int* __restrict__ slots, float* __restrict__ out,
    int Nrows) {
  __shared__ __bf16 ldsW[2][64 * WPAD];
  const int tid = threadIdx.x;
  const int wv = tid >> 6, lane = tid & 63;
  const int r = lane & 15, g = lane >> 4;
  int row = blockIdx.x * 64 + wv * 16 + r;
  if (row >= Nrows) row = Nrows - 1;  // duplicate rows write identical values
  const uint4* srow = (const uint4*)(slots + (size_t)row * NSLOT);

  // staging coords: thread copies W row c = tid>>2, elems [si, si+16)
  const int sc = tid >> 2;
  const int si = (tid & 3) * 16;

  // stage W[0]: pure vector copy (2 x 16B load, 2 x ds_write_b128)
  {
    const __bf16* wp = wt + sc * 64 + si;
    bf16x8 wa = *(const bf16x8*)(wp);
    bf16x8 wb = *(const bf16x8*)(wp + 8);
    *(bf16x8*)&ldsW[0][sc * WPAD + si] = wa;
    *(bf16x8*)&ldsW[0][sc * WPAD + si + 8] = wb;
  }

  // Cell pipeline: cur = k, nxt = k+1 (prefetched one body ahead).
  uint4 cellCur = srow[0];
  uint4 cellNxt = srow[1];

  f32x4 acc[4] = {f32x4{0.f, 0.f, 0.f, 0.f}, f32x4{0.f, 0.f, 0.f, 0.f},
                  f32x4{0.f, 0.f, 0.f, 0.f}, f32x4{0.f, 0.f, 0.f, 0.f}};
  __syncthreads();

  for (int k = 0; k < KOFF; ++k) {
    const int kb = k & 1;
    // (1) gather loads for k (cell already in registers) -- 8 independent 16B
    int gC[4] = {(int)cellCur.x, (int)cellCur.y, (int)cellCur.z,
                 (int)cellCur.w};
    bf16x8 fa[4], fc[4];
#pragma unroll
    for (int j = 0; j < 4; ++j) {
      if (gC[j] >= 0) {
        const __bf16* ap = fb + (size_t)gC[j] * 64 + g * 8;
        fa[j] = *(const bf16x8*)(ap);
        fc[j] = *(const bf16x8*)(ap + 32);
      }
    }
    // (2) W-load(k+1) into regs
    bf16x8 wa, wb;
    if (k + 1 < KOFF) {
      const __bf16* wp = wt + (size_t)(k + 1) * 4096 + sc * 64 + si;
      wa = *(const bf16x8*)(wp);
      wb = *(const bf16x8*)(wp + 8);
    }
    // (3) cell(k+2)
    uint4 cv2 = make_uint4(~0u, ~0u, ~0u, ~0u);
    if (k + 2 < KOFF) cv2 = srow[k + 2];
    // (4) presum(k) in f32 (linearity: sum before GEMM)
    float s0[8] = {0.f, 0.f, 0.f, 0.f, 0.f, 0.f, 0.f, 0.f};
    float s1[8] = {0.f, 0.f, 0.f, 0.f, 0.f, 0.f, 0.f, 0.f};
#pragma unroll
    for (int j = 0; j < 4; ++j) {
      if (gC[j] >= 0) {
#pragma unroll
        for (int q = 0; q < 8; ++q) {
          s0[q] += (float)fa[j][q];
          s1[q] += (float)fc[j][q];
        }
      }
    }
    bf16x8 b0, b1;
#pragma unroll
    for (int q = 0; q < 8; ++q) {
      b0[q] = (__bf16)s0[q];
      b1[q] = (__bf16)s1[q];
    }
    // (5) W fragments from LDS + 8 MFMAs into persistent acc
    bf16x8 w0f[4], w1f[4];
#pragma unroll
    for (int t = 0; t < 4; ++t) {
      w0f[t] = *(const bf16x8*)&ldsW[kb][(t * 16 + r) * WPAD + g * 8];
      w1f[t] = *(const bf16x8*)&ldsW[kb][(t * 16 + r) * WPAD + g * 8 + 32];
    }
#pragma unroll
    for (int t = 0; t < 4; ++t) {
      acc[t] = __builtin_amdgcn_mfma_f32_16x16x32_bf16(w0f[t], b0, acc[t], 0, 0, 0);
      acc[t] = __builtin_amdgcn_mfma_f32_16x16x32_bf16(w1f[t], b1, acc[t], 0, 0, 0);
    }
    // (6) ds_write W(k+1) into the other buffer + one barrier per k
    if (k + 1 < KOFF) {
      *(bf16x8*)&ldsW[kb ^ 1][sc * WPAD + si] = wa;
      *(bf16x8*)&ldsW[kb ^ 1][sc * WPAD + si + 8] = wb;
      __syncthreads();
    }
    // (7) rotate cell pipeline
    cellCur = cellNxt;
    cellNxt = cv2;
  }

  // Epilogue: lane (g,r) holds channels t*16+g*4+{0..3} of row.
  float* op = out + (size_t)row * 64;
#pragma unroll
  for (int t = 0; t < 4; ++t) *(f32x4*)(op + t * 16 + g * 4) = acc[t];
}

// ---- k4: overflow fixup (~500 pairs): recompute feat.W (bf16), atomicAdd ----
__global__ __launch_bounds__(256) void k4_fixup(
    const __bf16* __restrict__ fb, const __bf16* __restrict__ wt,
    const int* __restrict__ nin, const int2* __restrict__ ovf,
    const int* __restrict__ ovfcnt, float* __restrict__ out, int Lpairs) {
  int gid = blockIdx.x * 256 + threadIdx.x;
  int i = gid >> 6, c = gid & 63;
  int n = *ovfcnt;
  if (n > OVFCAP) n = OVFCAP;
  if (i >= n) return;
  int row = ovf[i].x, pid = ovf[i].y;
  int k = pid / Lpairs;
  int irow = nin[pid];
  const __bf16* wk = wt + ((size_t)k * 64 + c) * 64;  // wt[k][c][*]
  const __bf16* f = fb + (size_t)irow * 64;
  float s = 0.f;
#pragma unroll 8
  for (int q = 0; q < 64; ++q) s += (float)f[q] * (float)wk[q];
  atomicAdd(&out[(size_t)row * 64 + c], s);
}

// ---- Fallback: atomic kernel (exotic shapes / tiny ws) ----
__global__ __launch_bounds__(256) void spconv_atomic_kernel(
    const float* __restrict__ feat, const float* __restrict__ kern,
    const int* __restrict__ nin, const int* __restrict__ nout,
    float* __restrict__ out, int Lpairs, int blocksPerK) {
  __shared__ __bf16 ldsBT[64 * WPAD];
  const int bk = blockIdx.x / blocksPerK;
  const int chunk = blockIdx.x % blocksPerK;
  const float* kb = kern + bk * 4096;
  for (int idx = threadIdx.x; idx < 4096; idx += 256) {
    int i = idx >> 6, c = idx & 63;
    ldsBT[c * WPAD + i] = (__bf16)kb[idx];
  }
  __syncthreads();
  const int lane = threadIdx.x & 63;
  const int wave = threadIdx.x >> 6;
  const int r = lane & 15, g = lane >> 4;
  bf16x8 bfrag[2][4];
#pragma unroll
  for (int s = 0; s < 2; ++s)
#pragma unroll
    for (int t = 0; t < 4; ++t)
      bfrag[s][t] = *(const bf16x8*)&ldsBT[(t * 16 + r) * WPAD + g * 8 + s * 32];
  const int* ninK = nin + bk * Lpairs;
  const int* noutK = nout + bk * Lpairs;
  const int base0 = chunk * 512 + wave * 128;
  for (int it = 0; it < 8; ++it) {
    const int base = base0 + it * 16;
    if (base >= Lpairs) break;
    const int arow = ninK[base + r];
    const float* ap = feat + (size_t)arow * 64 + g * 8;
    f32x4 f0 = *(const f32x4*)(ap);
    f32x4 f1 = *(const f32x4*)(ap + 4);
    f32x4 f2 = *(const f32x4*)(ap + 32);
    f32x4 f3 = *(const f32x4*)(ap + 36);
    bf16x8 a0, a1;
#pragma unroll
    for (int j = 0; j < 4; ++j) {
      a0[j] = (__bf16)f0[j];
      a0[j + 4] = (__bf16)f1[j];
      a1[j] = (__bf16)f2[j];
      a1[j + 4] = (__bf16)f3[j];
    }
    f32x4 acc[4] = {f32x4{0.f, 0.f, 0.f, 0.f}, f32x4{0.f, 0.f, 0.f, 0.f},
                    f32x4{0.f, 0.f, 0.f, 0.f}, f32x4{0.f, 0.f, 0.f, 0.f}};
#pragma unroll
    for (int t = 0; t < 4; ++t) {
      acc[t] = __builtin_amdgcn_mfma_f32_16x16x32_bf16(a0, bfrag[0][t], acc[t], 0, 0, 0);
      acc[t] = __builtin_amdgcn_mfma_f32_16x16x32_bf16(a1, bfrag[1][t], acc[t], 0, 0, 0);
    }
    int orow[4];
#pragma unroll
    for (int reg = 0; reg < 4; ++reg) orow[reg] = noutK[base + g * 4 + reg];
#pragma unroll
    for (int t = 0; t < 4; ++t)
#pragma unroll
      for (int reg = 0; reg < 4; ++reg)
        atomicAdd(out + (size_t)orow[reg] * 64 + t * 16 + r, acc[t][reg]);
  }
}

extern "C" void kernel_launch(void* const* d_in, const int* in_sizes, int n_in,
                              void* d_out, int out_size, void* d_ws, size_t ws_size,
                              hipStream_t stream) {
  const float* feat = (const float*)d_in[0];
  const float* kern = (const float*)d_in[1];
  const int* nin = (const int*)d_in[2];
  const int* nout = (const int*)d_in[3];
  float* out = (float*)d_out;

  const int total = in_sizes[2];        // 27*L pairs
  const int Lpairs = total / KOFF;      // 50000
  const int Nrows = out_size / 64;      // 100000
  const int nElems = Nrows * 64;

  // ws layout: slots (u32 direct-row, 0xFF-init) | ovf | ovfcnt | wt | fb
  const size_t slotsBytes = (size_t)Nrows * NSLOT * 4;
  const size_t ovfOff = (slotsBytes + 255) & ~(size_t)255;
  const size_t cntOff = (ovfOff + (size_t)OVFCAP * 8 + 255) & ~(size_t)255;
  const size_t wtOff = (cntOff + 256 + 255) & ~(size_t)255;
  const size_t fbOff = (wtOff + (size_t)KOFF * 4096 * 2 + 255) & ~(size_t)255;
  const size_t needed = fbOff + (size_t)nElems * 2;

  const bool shapeOK = (Lpairs % 16 == 0) && (total % KOFF == 0) &&
                       (out_size % 64 == 0);

  if (shapeOK && ws_size >= needed) {
    unsigned int* slots = (unsigned int*)d_ws;
    int2* ovf = (int2*)((char*)d_ws + ovfOff);
    int* ovfcnt = (int*)((char*)d_ws + cntOff);
    __bf16* wt = (__bf16*)((char*)d_ws + wtOff);
    __bf16* fb = (__bf16*)((char*)d_ws + fbOff);

    hipMemsetAsync(slots, 0xFF, slotsBytes, stream);
    hipMemsetAsync(ovfcnt, 0, 4, stream);

    const int nchunk = (Nrows + ROWCHUNK - 1) / ROWCHUNK;
    const int rankBlocks = KOFF * nchunk;
    const int wtBlocks = (KOFF * 64 + ATHR - 1) / ATHR;  // 2
    const int castBlocks = (nElems / 8 + ATHR - 1) / ATHR;
    kA_rank_cast<<<rankBlocks + wtBlocks + castBlocks, ATHR, 0, stream>>>(
        feat, kern, nin, nout, fb, wt, slots, ovf, ovfcnt, Lpairs, nElems,
        nchunk, rankBlocks, wtBlocks);
    kF_fused<<<(Nrows + 63) / 64, 256, 0, stream>>>(fb, wt, slots, out, Nrows);
    k4_fixup<<<OVFCAP * 64 / 256, 256, 0, stream>>>(fb, wt, nin, ovf, ovfcnt,
                                                    out, Lpairs);
  } else {
    const int blocksPerK = (Lpairs + 511) / 512;
    hipMemsetAsync(d_out, 0, (size_t)out_size * sizeof(float), stream);
    spconv_atomic_kernel<<<KOFF * blocksPerK, 256, 0, stream>>>(
        feat, kern, nin, nout, out, Lpairs, blocksPerK);
  }
}

// Round 21
// 121.073 us; speedup vs baseline: 1.3378x; 1.0450x over previous
//
#include <hip/hip_runtime.h>
#include <hip/hip_bf16.h>

// Sparse conv for MI355X (gfx950), fused output-stationary design
// (r18 frame; single change: ROWCHUNK 8192 -> 16384 halves kA scan work):
//   kA : rank-blocks (LDS nibble counters -> DIRECT-ROW slot table
//        [row][27][4] u32) + wt-blocks (kern -> bf16 W^T) + cast-blocks
//        (f32 -> bf16 feature table fb). 1024 threads/block, depth-1 scan.
//   kF : 256-thread blocks, wave owns 16 rows; acc D[64ch][16rows] in regs
//        across all 27 k. Per k: 8 gathers from prefetched cell, presum
//        (linearity), 8 MFMAs vs W[k] from double-buffered LDS, 1 barrier/k.
//   k4 : overflow fixup (~500 pairs) recomputes feat.W, atomicAdd.
// Fallback to a pure-atomic kernel for exotic shapes / tiny ws.

typedef __bf16 bf16x8 __attribute__((ext_vector_type(8)));
typedef float f32x4 __attribute__((ext_vector_type(4)));

#define KOFF 27
#define SLOTK 4                 // slots per (row,k) cell
#define NSLOT (KOFF * SLOTK)    // 108 entries per row
#define OVFCAP 8192             // overflow list capacity (E[ovf] ~ 505)
#define WPAD 72                 // LDS pad for W tile
#define ROWCHUNK 16384          // rows per rank-block chunk (r21: was 8192)
#define NIBW (ROWCHUNK / 8)     // 8 KB LDS nibble counters
#define ATHR 1024               // kA block size

// ---- kA: chunked rank-builder (direct-row slots) + W cast + feature cast ----
__global__ __launch_bounds__(ATHR) void kA_rank_cast(
    const float* __restrict__ feat, const float* __restrict__ kern,
    const int* __restrict__ nin, const int* __restrict__ nout,
    __bf16* __restrict__ fb, __bf16* __restrict__ wt,
    unsigned int* __restrict__ slots, int2* __restrict__ ovf,
    int* __restrict__ ovfcnt, int Lpairs, int nElems, int nchunk,
    int rankBlocks, int wtBlocks) {
  __shared__ unsigned int nib[NIBW];
  const int tid = threadIdx.x;
  if ((int)blockIdx.x < rankBlocks) {
    const int k = blockIdx.x / nchunk;
    const int chunk = blockIdx.x % nchunk;
    const int lo = chunk * ROWCHUNK;
    for (int i = tid; i < NIBW; i += ATHR) nib[i] = 0u;
    __syncthreads();
    const int* nkO = nout + k * Lpairs;
    const int* nkI = nin + k * Lpairs;
    const int STEP = ATHR * 8;  // 8192 pairs per iteration

    // depth-1 pipelined scan: load batch(base+STEP) while claiming batch(base)
    int l[8], row[8], rin[8], ln[8], rown[8], rinn[8];
#pragma unroll
    for (int j = 0; j < 8; ++j) {
      l[j] = j * ATHR + tid;
      row[j] = (l[j] < Lpairs) ? nkO[l[j]] : -1;
      rin[j] = (l[j] < Lpairs) ? nkI[l[j]] : 0;
    }
    for (int base = 0; base < Lpairs; base += STEP) {
      const int nbase = base + STEP;
      if (nbase < Lpairs) {
#pragma unroll
        for (int j = 0; j < 8; ++j) {
          ln[j] = nbase + j * ATHR + tid;
          rown[j] = (ln[j] < Lpairs) ? nkO[ln[j]] : -1;
          rinn[j] = (ln[j] < Lpairs) ? nkI[ln[j]] : 0;
        }
      }
#pragma unroll
      for (int j = 0; j < 8; ++j) {
        int rr = row[j] - lo;
        if (rr >= 0 && rr < ROWCHUNK) {
          unsigned int sh = ((unsigned)rr & 7u) * 4u;
          unsigned int old = atomicAdd(&nib[rr >> 3], 1u << sh);
          int rank = (old >> sh) & 15;
          if (rank < SLOTK) {
            slots[(size_t)row[j] * NSLOT + k * SLOTK + rank] =
                (unsigned int)rin[j];
          } else {
            int idx = atomicAdd(ovfcnt, 1);
            if (idx < OVFCAP) ovf[idx] = make_int2(row[j], k * Lpairs + l[j]);
          }
        }
      }
      if (nbase < Lpairs) {
#pragma unroll
        for (int j = 0; j < 8; ++j) {
          l[j] = ln[j];
          row[j] = rown[j];
          rin[j] = rinn[j];
        }
      }
    }
  } else if ((int)blockIdx.x < rankBlocks + wtBlocks) {
    // W transpose/cast: wt[k][c*64+i] = (bf16)kern[k*4096 + i*64 + c]
    int kc = (blockIdx.x - rankBlocks) * ATHR + tid;
    if (kc < KOFF * 64) {
      int k = kc >> 6, c = kc & 63;
      const float* src = kern + k * 4096 + c;
      __bf16* dst = wt + (size_t)kc * 64;
#pragma unroll
      for (int i0 = 0; i0 < 64; i0 += 8) {
        bf16x8 v;
#pragma unroll
        for (int q = 0; q < 8; ++q) v[q] = (__bf16)src[(i0 + q) * 64];
        *(bf16x8*)(dst + i0) = v;
      }
    }
  } else {
    int i = ((blockIdx.x - rankBlocks - wtBlocks) * ATHR + tid) * 8;
    if (i < nElems) {
      f32x4 a = *(const f32x4*)(feat + i);
      f32x4 b = *(const f32x4*)(feat + i + 4);
      bf16x8 v;
#pragma unroll
      for (int j = 0; j < 4; ++j) {
        v[j] = (__bf16)a[j];
        v[j + 4] = (__bf16)b[j];
      }
      *(bf16x8*)(fb + i) = v;
    }
  }
}

// ---- kF: fused output-stationary GEMM (r10 schedule, direct-row cells) ----
// Wave handles 16 rows. Lane (g=lane>>4, r=lane&15):
//   B operand per k: summed cell features of row (rowbase+r)
//   A operand: W[k]^T fragments from LDS (staged from wt via b128 copies)
//   D: col=r -> row, row=g*4+reg (+t*16) -> channel; persistent across k.
__global__ __launch_bounds__(256) void kF_fused(
    const __bf16* __restrict__ fb, const __bf16* __restrict__ wt,
    const unsigned int* __restrict__ slots, float* __restrict__ out,
    int Nrows) {
  __shared__ __bf16 ldsW[2][64 * WPAD];
  const int tid = threadIdx.x;
  const int wv = tid >> 6, lane = tid & 63;
  const int r = lane & 15, g = lane >> 4;
  int row = blockIdx.x * 64 + wv * 16 + r;
  if (row >= Nrows) row = Nrows - 1;  // duplicate rows write identical values
  const uint4* srow = (const uint4*)(slots + (size_t)row * NSLOT);

  // staging coords: thread copies W row c = tid>>2, elems [si, si+16)
  const int sc = tid >> 2;
  const int si = (tid & 3) * 16;

  // stage W[0]: pure vector copy (2 x 16B load, 2 x ds_write_b128)
  {
    const __bf16* wp = wt + sc * 64 + si;
    bf16x8 wa = *(const bf16x8*)(wp);
    bf16x8 wb = *(const bf16x8*)(wp + 8);
    *(bf16x8*)&ldsW[0][sc * WPAD + si] = wa;
    *(bf16x8*)&ldsW[0][sc * WPAD + si + 8] = wb;
  }

  // Cell pipeline: cur = k, nxt = k+1 (prefetched one body ahead).
  uint4 cellCur = srow[0];
  uint4 cellNxt = srow[1];

  f32x4 acc[4] = {f32x4{0.f, 0.f, 0.f, 0.f}, f32x4{0.f, 0.f, 0.f, 0.f},
                  f32x4{0.f, 0.f, 0.f, 0.f}, f32x4{0.f, 0.f, 0.f, 0.f}};
  __syncthreads();

  for (int k = 0; k < KOFF; ++k) {
    const int kb = k & 1;
    // (1) gather loads for k (cell already in registers) -- 8 independent 16B
    int gC[4] = {(int)cellCur.x, (int)cellCur.y, (int)cellCur.z,
                 (int)cellCur.w};
    bf16x8 fa[4], fc[4];
#pragma unroll
    for (int j = 0; j < 4; ++j) {
      if (gC[j] >= 0) {
        const __bf16* ap = fb + (size_t)gC[j] * 64 + g * 8;
        fa[j] = *(const bf16x8*)(ap);
        fc[j] = *(const bf16x8*)(ap + 32);
      }
    }
    // (2) W-load(k+1) into regs
    bf16x8 wa, wb;
    if (k + 1 < KOFF) {
      const __bf16* wp = wt + (size_t)(k + 1) * 4096 + sc * 64 + si;
      wa = *(const bf16x8*)(wp);
      wb = *(const bf16x8*)(wp + 8);
    }
    // (3) cell(k+2)
    uint4 cv2 = make_uint4(~0u, ~0u, ~0u, ~0u);
    if (k + 2 < KOFF) cv2 = srow[k + 2];
    // (4) presum(k) in f32 (linearity: sum before GEMM)
    float s0[8] = {0.f, 0.f, 0.f, 0.f, 0.f, 0.f, 0.f, 0.f};
    float s1[8] = {0.f, 0.f, 0.f, 0.f, 0.f, 0.f, 0.f, 0.f};
#pragma unroll
    for (int j = 0; j < 4; ++j) {
      if (gC[j] >= 0) {
#pragma unroll
        for (int q = 0; q < 8; ++q) {
          s0[q] += (float)fa[j][q];
          s1[q] += (float)fc[j][q];
        }
      }
    }
    bf16x8 b0, b1;
#pragma unroll
    for (int q = 0; q < 8; ++q) {
      b0[q] = (__bf16)s0[q];
      b1[q] = (__bf16)s1[q];
    }
    // (5) W fragments from LDS + 8 MFMAs into persistent acc
    bf16x8 w0f[4], w1f[4];
#pragma unroll
    for (int t = 0; t < 4; ++t) {
      w0f[t] = *(const bf16x8*)&ldsW[kb][(t * 16 + r) * WPAD + g * 8];
      w1f[t] = *(const bf16x8*)&ldsW[kb][(t * 16 + r) * WPAD + g * 8 + 32];
    }
#pragma unroll
    for (int t = 0; t < 4; ++t) {
      acc[t] = __builtin_amdgcn_mfma_f32_16x16x32_bf16(w0f[t], b0, acc[t], 0, 0, 0);
      acc[t] = __builtin_amdgcn_mfma_f32_16x16x32_bf16(w1f[t], b1, acc[t], 0, 0, 0);
    }
    // (6) ds_write W(k+1) into the other buffer + one barrier per k
    if (k + 1 < KOFF) {
      *(bf16x8*)&ldsW[kb ^ 1][sc * WPAD + si] = wa;
      *(bf16x8*)&ldsW[kb ^ 1][sc * WPAD + si + 8] = wb;
      __syncthreads();
    }
    // (7) rotate cell pipeline
    cellCur = cellNxt;
    cellNxt = cv2;
  }

  // Epilogue: lane (g,r) holds channels t*16+g*4+{0..3} of row.
  float* op = out + (size_t)row * 64;
#pragma unroll
  for (int t = 0; t < 4; ++t) *(f32x4*)(op + t * 16 + g * 4) = acc[t];
}

// ---- k4: overflow fixup (~500 pairs): recompute feat.W (bf16), atomicAdd ----
__global__ __launch_bounds__(256) void k4_fixup(
    const __bf16* __restrict__ fb, const __bf16* __restrict__ wt,
    const int* __restrict__ nin, const int2* __restrict__ ovf,
    const int* __restrict__ ovfcnt, float* __restrict__ out, int Lpairs) {
  int gid = blockIdx.x * 256 + threadIdx.x;
  int i = gid >> 6, c = gid & 63;
  int n = *ovfcnt;
  if (n > OVFCAP) n = OVFCAP;
  if (i >= n) return;
  int row = ovf[i].x, pid = ovf[i].y;
  int k = pid / Lpairs;
  int irow = nin[pid];
  const __bf16* wk = wt + ((size_t)k * 64 + c) * 64;  // wt[k][c][*]
  const __bf16* f = fb + (size_t)irow * 64;
  float s = 0.f;
#pragma unroll 8
  for (int q = 0; q < 64; ++q) s += (float)f[q] * (float)wk[q];
  atomicAdd(&out[(size_t)row * 64 + c], s);
}

// ---- Fallback: atomic kernel (exotic shapes / tiny ws) ----
__global__ __launch_bounds__(256) void spconv_atomic_kernel(
    const float* __restrict__ feat, const float* __restrict__ kern,
    const int* __restrict__ nin, const int* __restrict__ nout,
    float* __restrict__ out, int Lpairs, int blocksPerK) {
  __shared__ __bf16 ldsBT[64 * WPAD];
  const int bk = blockIdx.x / blocksPerK;
  const int chunk = blockIdx.x % blocksPerK;
  const float* kb = kern + bk * 4096;
  for (int idx = threadIdx.x; idx < 4096; idx += 256) {
    int i = idx >> 6, c = idx & 63;
    ldsBT[c * WPAD + i] = (__bf16)kb[idx];
  }
  __syncthreads();
  const int lane = threadIdx.x & 63;
  const int wave = threadIdx.x >> 6;
  const int r = lane & 15, g = lane >> 4;
  bf16x8 bfrag[2][4];
#pragma unroll
  for (int s = 0; s < 2; ++s)
#pragma unroll
    for (int t = 0; t < 4; ++t)
      bfrag[s][t] = *(const bf16x8*)&ldsBT[(t * 16 + r) * WPAD + g * 8 + s * 32];
  const int* ninK = nin + bk * Lpairs;
  const int* noutK = nout + bk * Lpairs;
  const int base0 = chunk * 512 + wave * 128;
  for (int it = 0; it < 8; ++it) {
    const int base = base0 + it * 16;
    if (base >= Lpairs) break;
    const int arow = ninK[base + r];
    const float* ap = feat + (size_t)arow * 64 + g * 8;
    f32x4 f0 = *(const f32x4*)(ap);
    f32x4 f1 = *(const f32x4*)(ap + 4);
    f32x4 f2 = *(const f32x4*)(ap + 32);
    f32x4 f3 = *(const f32x4*)(ap + 36);
    bf16x8 a0, a1;
#pragma unroll
    for (int j = 0; j < 4; ++j) {
      a0[j] = (__bf16)f0[j];
      a0[j + 4] = (__bf16)f1[j];
      a1[j] = (__bf16)f2[j];
      a1[j + 4] = (__bf16)f3[j];
    }
    f32x4 acc[4] = {f32x4{0.f, 0.f, 0.f, 0.f}, f32x4{0.f, 0.f, 0.f, 0.f},
                    f32x4{0.f, 0.f, 0.f, 0.f}, f32x4{0.f, 0.f, 0.f, 0.f}};
#pragma unroll
    for (int t = 0; t < 4; ++t) {
      acc[t] = __builtin_amdgcn_mfma_f32_16x16x32_bf16(a0, bfrag[0][t], acc[t], 0, 0, 0);
      acc[t] = __builtin_amdgcn_mfma_f32_16x16x32_bf16(a1, bfrag[1][t], acc[t], 0, 0, 0);
    }
    int orow[4];
#pragma unroll
    for (int reg = 0; reg < 4; ++reg) orow[reg] = noutK[base + g * 4 + reg];
#pragma unroll
    for (int t = 0; t < 4; ++t)
#pragma unroll
      for (int reg = 0; reg < 4; ++reg)
        atomicAdd(out + (size_t)orow[reg] * 64 + t * 16 + r, acc[t][reg]);
  }
}

extern "C" void kernel_launch(void* const* d_in, const int* in_sizes, int n_in,
                              void* d_out, int out_size, void* d_ws, size_t ws_size,
                              hipStream_t stream) {
  const float* feat = (const float*)d_in[0];
  const float* kern = (const float*)d_in[1];
  const int* nin = (const int*)d_in[2];
  const int* nout = (const int*)d_in[3];
  float* out = (float*)d_out;

  const int total = in_sizes[2];        // 27*L pairs
  const int Lpairs = total / KOFF;      // 50000
  const int Nrows = out_size / 64;      // 100000
  const int nElems = Nrows * 64;

  // ws layout: slots (u32 direct-row, 0xFF-init) | ovf | ovfcnt | wt | fb
  const size_t slotsBytes = (size_t)Nrows * NSLOT * 4;
  const size_t ovfOff = (slotsBytes + 255) & ~(size_t)255;
  const size_t cntOff = (ovfOff + (size_t)OVFCAP * 8 + 255) & ~(size_t)255;
  const size_t wtOff = (cntOff + 256 + 255) & ~(size_t)255;
  const size_t fbOff = (wtOff + (size_t)KOFF * 4096 * 2 + 255) & ~(size_t)255;
  const size_t needed = fbOff + (size_t)nElems * 2;

  const bool shapeOK = (Lpairs % 16 == 0) && (total % KOFF == 0) &&
                       (out_size % 64 == 0);

  if (shapeOK && ws_size >= needed) {
    unsigned int* slots = (unsigned int*)d_ws;
    int2* ovf = (int2*)((char*)d_ws + ovfOff);
    int* ovfcnt = (int*)((char*)d_ws + cntOff);
    __bf16* wt = (__bf16*)((char*)d_ws + wtOff);
    __bf16* fb = (__bf16*)((char*)d_ws + fbOff);

    hipMemsetAsync(slots, 0xFF, slotsBytes, stream);
    hipMemsetAsync(ovfcnt, 0, 4, stream);

    const int nchunk = (Nrows + ROWCHUNK - 1) / ROWCHUNK;
    const int rankBlocks = KOFF * nchunk;
    const int wtBlocks = (KOFF * 64 + ATHR - 1) / ATHR;  // 2
    const int castBlocks = (nElems / 8 + ATHR - 1) / ATHR;
    kA_rank_cast<<<rankBlocks + wtBlocks + castBlocks, ATHR, 0, stream>>>(
        feat, kern, nin, nout, fb, wt, slots, ovf, ovfcnt, Lpairs, nElems,
        nchunk, rankBlocks, wtBlocks);
    kF_fused<<<(Nrows + 63) / 64, 256, 0, stream>>>(fb, wt, slots, out, Nrows);
    k4_fixup<<<OVFCAP * 64 / 256, 256, 0, stream>>>(fb, wt, nin, ovf, ovfcnt,
                                                    out, Lpairs);
  } else {
    const int blocksPerK = (Lpairs + 511) / 512;
    hipMemsetAsync(d_out, 0, (size_t)out_size * sizeof(float), stream);
    spconv_atomic_kernel<<<KOFF * blocksPerK, 256, 0, stream>>>(
        feat, kern, nin, nout, out, Lpairs, blocksPerK);
  }
}